// Round 18
// baseline (107.638 us; speedup 1.0000x reference)
//
#include <hip/hip_runtime.h>
#include <hip/hip_bf16.h>
#include <hip/hip_fp16.h>

// GAT layer, CSR-by-destination (R15/R17 structure), ~12.2 MB ws, zero global
// atomics, 5 launches:
//   keys = inputs @ W1 + b1            (stored bf16; alphas from f32 accumulator)
//   logit[e] = leaky(a_src[s] + a_dst[d] + a_ee[ty] + b2)
//   attn = exp/segsum ; out[d] = sum attn*(keys[s]+ee[ty])
// R18: k_nodes GEMM does 2 rows per W1 LDS read (32 rows/block) -> LDS BW per
// output halved (was the k_nodes wall: 64 ds_read_b128/wave/k-iter ~ 10us).

__device__ __forceinline__ unsigned short f2bf(float f) {
    unsigned u = __float_as_uint(f);
    u += 0x7FFFu + ((u >> 16) & 1u);          // round-nearest-even
    return (unsigned short)(u >> 16);
}
__device__ __forceinline__ float bf2f(unsigned short h) {
    return __uint_as_float(((unsigned)h) << 16);
}

#define NBLK_H 256        // edge chunks for histogram/scatter
#define CAPB   16384      // LDS edge-stage capacity per bucket (4x statistical max)

// GEMM (32 rows/block, 2 rows per thread) + alphas + fused bucket histogram
__global__ __launch_bounds__(256) void k_nodes(
    const float* __restrict__ inputs, const float* __restrict__ W1,
    const float* __restrict__ b1, const float* __restrict__ W2,
    const float* __restrict__ edge_emb, const int* __restrict__ dst,
    unsigned short* __restrict__ keys, float* __restrict__ alpha_src,
    float* __restrict__ alpha_dst, float* __restrict__ alpha_ee,
    int* __restrict__ histG, int N, int E, int NB, int chunk)
{
    __shared__ float W1s[64 * 64];
    __shared__ float W2s[128];
    __shared__ float xs[32 * 65];
    __shared__ int histL[256];

    const int t = threadIdx.x;
    const int row0 = blockIdx.x * 32;

    const float4* W1g = reinterpret_cast<const float4*>(W1);
    float4* W1sv = reinterpret_cast<float4*>(W1s);
#pragma unroll
    for (int i = 0; i < 4; i++) W1sv[t + 256 * i] = W1g[t + 256 * i];
    if (t < 128) W2s[t] = W2[t];

#pragma unroll
    for (int i = 0; i < 8; i++) {
        int idx = t + 256 * i;               // 0..2047
        int r = idx >> 6, c = idx & 63;
        if (row0 + r < N)
            xs[r * 65 + c] = inputs[(size_t)(row0 + r) * 64 + c];
    }
    __syncthreads();

    const int lane = t & 63;
    const int wave = t >> 6;
    const int gidx = wave * 4 + (lane >> 4);   // 16-lane group id 0..15
    const int j4   = lane & 15;                // float4 column group
    const int rA = 2 * gidx, rB = 2 * gidx + 1;
    const int rowA = row0 + rA, rowB = row0 + rB;

    const float4* W1v = reinterpret_cast<const float4*>(W1s);
    float4 acc0 = {0.f, 0.f, 0.f, 0.f};
    float4 acc1 = {0.f, 0.f, 0.f, 0.f};
#pragma unroll
    for (int k = 0; k < 64; k++) {
        float4 w = W1v[k * 16 + j4];           // ONE LDS b128 read feeds 8 FMA
        float a0 = xs[rA * 65 + k];            // broadcast within group
        float a1 = xs[rB * 65 + k];
        acc0.x += a0 * w.x; acc0.y += a0 * w.y; acc0.z += a0 * w.z; acc0.w += a0 * w.w;
        acc1.x += a1 * w.x; acc1.y += a1 * w.y; acc1.z += a1 * w.z; acc1.w += a1 * w.w;
    }

    float4 bv = reinterpret_cast<const float4*>(b1)[j4];
    if (rowA < N) {
        float4 a = { acc0.x + bv.x, acc0.y + bv.y, acc0.z + bv.z, acc0.w + bv.w };
        ushort4 kv; kv.x = f2bf(a.x); kv.y = f2bf(a.y); kv.z = f2bf(a.z); kv.w = f2bf(a.w);
        reinterpret_cast<ushort4*>(keys)[(size_t)rowA * 16 + j4] = kv;
        float p1 = a.x * W2s[4 * j4]     + a.y * W2s[4 * j4 + 1]
                 + a.z * W2s[4 * j4 + 2] + a.w * W2s[4 * j4 + 3];
        float p2 = a.x * W2s[64 + 4 * j4]     + a.y * W2s[64 + 4 * j4 + 1]
                 + a.z * W2s[64 + 4 * j4 + 2] + a.w * W2s[64 + 4 * j4 + 3];
#pragma unroll
        for (int m = 8; m >= 1; m >>= 1) {
            p1 += __shfl_xor(p1, m);
            p2 += __shfl_xor(p2, m);
        }
        if (j4 == 0) { alpha_src[rowA] = p1; alpha_dst[rowA] = p2; }
    }
    if (rowB < N) {
        float4 a = { acc1.x + bv.x, acc1.y + bv.y, acc1.z + bv.z, acc1.w + bv.w };
        ushort4 kv; kv.x = f2bf(a.x); kv.y = f2bf(a.y); kv.z = f2bf(a.z); kv.w = f2bf(a.w);
        reinterpret_cast<ushort4*>(keys)[(size_t)rowB * 16 + j4] = kv;
        float p1 = a.x * W2s[4 * j4]     + a.y * W2s[4 * j4 + 1]
                 + a.z * W2s[4 * j4 + 2] + a.w * W2s[4 * j4 + 3];
        float p2 = a.x * W2s[64 + 4 * j4]     + a.y * W2s[64 + 4 * j4 + 1]
                 + a.z * W2s[64 + 4 * j4 + 2] + a.w * W2s[64 + 4 * j4 + 3];
#pragma unroll
        for (int m = 8; m >= 1; m >>= 1) {
            p1 += __shfl_xor(p1, m);
            p2 += __shfl_xor(p2, m);
        }
        if (j4 == 0) { alpha_src[rowB] = p1; alpha_dst[rowB] = p2; }
    }

    if (blockIdx.x == 0 && t < 6) {
        float s = 0.f;
        for (int c = 0; c < 64; c++) s += edge_emb[t * 64 + c] * W2s[c];
        alpha_ee[t] = s;
    }

    // fused histogram (bucket = dst>>8): blockIdx uniform -> barriers safe
    if (blockIdx.x < NBLK_H) {
        const int blk = blockIdx.x;
        for (int b = t; b < NB; b += 256) histL[b] = 0;
        __syncthreads();
        const int lim = min(E, (blk + 1) * chunk);
        for (int e = blk * chunk + t; e < lim; e += 256)
            atomicAdd(&histL[dst[e] >> 8], 1);
        __syncthreads();
        for (int b = t; b < NB; b += 256)
            histG[b * NBLK_H + blk] = histL[b];
    }
}

// per-bucket row scan: exclusive over the 256 chunk-counts, total -> bsum[b]
__global__ __launch_bounds__(256) void k_scanA(
    int* __restrict__ histG, int* __restrict__ bsum)
{
    __shared__ int sm[256];
    const int t = threadIdx.x;
    const int b = blockIdx.x;
    int v = histG[b * NBLK_H + t];
    sm[t] = v;
    __syncthreads();
    for (int off = 1; off < 256; off <<= 1) {
        int x = 0;
        if (t >= off) x = sm[t - off];
        __syncthreads();
        if (t >= off) sm[t] += x;
        __syncthreads();
    }
    histG[b * NBLK_H + t] = sm[t] - v;     // exclusive
    if (t == 255) bsum[b] = sm[255];
}

// scatter into bucket-sorted order; boff derived locally from bsum (LDS scan)
__global__ __launch_bounds__(256) void k_bucket_scatter(
    const int* __restrict__ src, const int* __restrict__ dst,
    const int* __restrict__ ety, const int* __restrict__ histG,
    const int* __restrict__ bsum, int* __restrict__ ebuf,
    int E, int NB, int chunk)
{
    __shared__ int sm[256];
    __shared__ int cur[256];
    const int t = threadIdx.x;
    const int blk = blockIdx.x;

    int bs = (t < NB) ? bsum[t] : 0;
    sm[t] = bs;
    __syncthreads();
    for (int off = 1; off < 256; off <<= 1) {
        int x = 0;
        if (t >= off) x = sm[t - off];
        __syncthreads();
        if (t >= off) sm[t] += x;
        __syncthreads();
    }
    if (t < NB) cur[t] = (sm[t] - bs) + histG[t * NBLK_H + blk];  // boff[t] + chunk offset
    __syncthreads();

    const int lim = min(E, (blk + 1) * chunk);
    for (int e = blk * chunk + t; e < lim; e += 256) {
        int d = dst[e];
        int pos = atomicAdd(&cur[d >> 8], 1);
        ebuf[pos] = src[e] | (ety[e] << 16) | ((d & 255) << 19);
    }
}

// one block per bucket: stage edges in LDS, 256-way sub-histogram + scan,
// write row_ptr, regroup in-place by dest, compute exp ONCE per edge ->
// wexp f16 (coalesced) + per-dest dsum via LDS float atomics.
__global__ __launch_bounds__(256) void k_localcsr(
    int* __restrict__ ebuf, const int* __restrict__ bsum,
    const float* __restrict__ a_src, const float* __restrict__ a_dst,
    const float* __restrict__ a_ee, const float* __restrict__ b2,
    int* __restrict__ rp, __half* __restrict__ wexp,
    float* __restrict__ dsum, int N, int NB, int E)
{
    __shared__ int   estage[CAPB];
    __shared__ int   h[256];
    __shared__ int   sm[256];
    __shared__ int   cur2[256];
    __shared__ float fsum[256];
    __shared__ float baseL[256];
    __shared__ float aeeL[8];

    const int t = threadIdx.x;
    const int b = blockIdx.x;
    const int idx = (b << 8) + t;

    int bs = (t < NB) ? bsum[t] : 0;
    sm[t] = bs;
    __syncthreads();
    for (int off = 1; off < 256; off <<= 1) {
        int x = 0;
        if (t >= off) x = sm[t - off];
        __syncthreads();
        if (t >= off) sm[t] += x;
        __syncthreads();
    }
    const int begB = (b == 0) ? 0 : sm[b - 1];
    const int endB = sm[b];
    const int cnt  = endB - begB;
    __syncthreads();

    h[t] = 0;
    fsum[t] = 0.f;
    baseL[t] = (idx < N) ? (a_dst[idx] + b2[0]) : 0.f;
    if (t < 6) aeeL[t] = a_ee[t];
    __syncthreads();

    for (int i = t; i < cnt; i += 256) {
        int r = ebuf[begB + i];
        if (i < CAPB) estage[i] = r;
        atomicAdd(&h[(r >> 19) & 255], 1);
    }
    __syncthreads();

    sm[t] = h[t];
    __syncthreads();
    for (int off = 1; off < 256; off <<= 1) {
        int x = 0;
        if (t >= off) x = sm[t - off];
        __syncthreads();
        if (t >= off) sm[t] += x;
        __syncthreads();
    }
    int lstart = (t == 0) ? 0 : sm[t - 1];

    if (idx < N) rp[idx] = begB + lstart;
    if (b == NB - 1 && t == 0) rp[N] = E;
    cur2[t] = begB + lstart;
    __syncthreads();

    for (int i = t; i < cnt; i += 256) {
        int r = (i < CAPB) ? estage[i] : ebuf[begB + i];
        int s  = r & 0xFFFF;
        int ty = (r >> 16) & 7;
        int dl = (r >> 19) & 255;
        float l = a_src[s] + aeeL[ty] + baseL[dl];
        l = fmaxf(0.2f * l, l);
        float w = expf(l);
        int pos = atomicAdd(&cur2[dl], 1);
        ebuf[pos] = r & 0x7FFFF;               // src | ty<<16
        wexp[pos] = __float2half_rn(w);
        atomicAdd(&fsum[dl], w);
    }
    __syncthreads();
    if (idx < N) dsum[idx] = fsum[t];
}

// one 64-lane wave per destination; exp-free single pass (R17 x2 unroll).
__global__ __launch_bounds__(256) void k_out(
    const int* __restrict__ rp, const int* __restrict__ erec,
    const __half* __restrict__ wexp, const float* __restrict__ dsum,
    const unsigned short* __restrict__ keys, const float* __restrict__ edge_emb,
    float* __restrict__ out, int N)
{
    __shared__ float ee4[384];
    __shared__ int   srec[4][64];
    __shared__ float sw[4][64];

    const int t = threadIdx.x;
    for (int i = t; i < 384; i += 256) ee4[i] = edge_emb[i];
    __syncthreads();

    const int lane = t & 63;
    const int wid  = t >> 6;
    const int d = blockIdx.x * 4 + wid;
    if (d >= N) return;

    const int beg = rp[d], end = rp[d + 1];
    const float inv = (end > beg) ? 1.f / dsum[d] : 0.f;

    const int g  = lane >> 4;
    const int j4 = lane & 15;
    const float4* ee4v = reinterpret_cast<const float4*>(ee4);
    float4 acc0 = {0.f, 0.f, 0.f, 0.f};
    float4 acc1 = {0.f, 0.f, 0.f, 0.f};

    for (int cbase = beg; cbase < end; cbase += 64) {
        const int n = min(64, end - cbase);
        if (lane < n) {
            srec[wid][lane] = erec[cbase + lane];
            sw[wid][lane]   = __half2float(wexp[cbase + lane]);
        }
        __builtin_amdgcn_wave_barrier();
        int j = g;
        for (; j + 4 < n; j += 8) {
            int   r0 = srec[wid][j];
            int   r1 = srec[wid][j + 4];
            float w0 = sw[wid][j];
            float w1 = sw[wid][j + 4];
            int sA = r0 & 0xFFFF, tyA = r0 >> 16;
            int sB = r1 & 0xFFFF, tyB = r1 >> 16;
            ushort4 kv0 = reinterpret_cast<const ushort4*>(keys)[(size_t)sA * 16 + j4];
            ushort4 kv1 = reinterpret_cast<const ushort4*>(keys)[(size_t)sB * 16 + j4];
            float4  ev0 = ee4v[tyA * 16 + j4];
            float4  ev1 = ee4v[tyB * 16 + j4];
            acc0.x += (bf2f(kv0.x) + ev0.x) * w0;
            acc0.y += (bf2f(kv0.y) + ev0.y) * w0;
            acc0.z += (bf2f(kv0.z) + ev0.z) * w0;
            acc0.w += (bf2f(kv0.w) + ev0.w) * w0;
            acc1.x += (bf2f(kv1.x) + ev1.x) * w1;
            acc1.y += (bf2f(kv1.y) + ev1.y) * w1;
            acc1.z += (bf2f(kv1.z) + ev1.z) * w1;
            acc1.w += (bf2f(kv1.w) + ev1.w) * w1;
        }
        if (j < n) {
            int   r0 = srec[wid][j];
            float w0 = sw[wid][j];
            int sA = r0 & 0xFFFF, tyA = r0 >> 16;
            ushort4 kv0 = reinterpret_cast<const ushort4*>(keys)[(size_t)sA * 16 + j4];
            float4  ev0 = ee4v[tyA * 16 + j4];
            acc0.x += (bf2f(kv0.x) + ev0.x) * w0;
            acc0.y += (bf2f(kv0.y) + ev0.y) * w0;
            acc0.z += (bf2f(kv0.z) + ev0.z) * w0;
            acc0.w += (bf2f(kv0.w) + ev0.w) * w0;
        }
        __builtin_amdgcn_wave_barrier();
    }

    float4 acc = { acc0.x + acc1.x, acc0.y + acc1.y,
                   acc0.z + acc1.z, acc0.w + acc1.w };
#pragma unroll
    for (int m = 16; m <= 32; m <<= 1) {
        acc.x += __shfl_xor(acc.x, m);
        acc.y += __shfl_xor(acc.y, m);
        acc.z += __shfl_xor(acc.z, m);
        acc.w += __shfl_xor(acc.w, m);
    }
    if (g == 0) {
        acc.x *= inv; acc.y *= inv; acc.z *= inv; acc.w *= inv;
        reinterpret_cast<float4*>(out)[(size_t)d * 16 + j4] = acc;
    }
}

extern "C" void kernel_launch(void* const* d_in, const int* in_sizes, int n_in,
                              void* d_out, int out_size, void* d_ws, size_t ws_size,
                              hipStream_t stream) {
    const float* inputs   = (const float*)d_in[0];
    const int*   src      = (const int*)d_in[1];
    const int*   dst      = (const int*)d_in[2];
    const int*   ety      = (const int*)d_in[3];
    const float* W1       = (const float*)d_in[5];
    const float* b1       = (const float*)d_in[6];
    const float* W2       = (const float*)d_in[7];
    const float* b2       = (const float*)d_in[8];
    const float* edge_emb = (const float*)d_in[9];
    float* out = (float*)d_out;

    const int N  = in_sizes[0] / 64;
    const int E  = in_sizes[1];
    const int NB = (N + 255) >> 8;          // 196 buckets of 256 dests
    const int M  = NB * NBLK_H;             // histG length (bucket-major)
    const int chunk = (E + NBLK_H - 1) / NBLK_H;

    // workspace layout in 4-byte units; total ~12.2 MB
    float*          ws      = (float*)d_ws;
    unsigned short* keys    = (unsigned short*)ws;          // N*64 bf16 = N*32 ints
    float*          a_src   = ws + (size_t)N * 32;          // N
    float*          a_dst   = a_src + N;                    // N
    float*          a_ee    = a_dst + N;                    // 8
    int*            rp      = (int*)(a_ee + 8);             // N+2
    int*            histG   = rp + (N + 2);                 // M
    int*            bsum    = histG + M;                    // 256
    int*            ebuf    = bsum + 256;                   // E
    __half*         wexp    = (__half*)(ebuf + E);          // E halves
    float*          dsum    = (float*)(wexp + ((E + 1) & ~1)); // N

    int nblk = (N + 31) / 32;               // 32 rows per block (>=256 for hist)
    k_nodes<<<nblk, 256, 0, stream>>>(inputs, W1, b1, W2, edge_emb, dst,
                                      keys, a_src, a_dst, a_ee, histG, N, E, NB, chunk);
    k_scanA<<<NB, 256, 0, stream>>>(histG, bsum);
    k_bucket_scatter<<<NBLK_H, 256, 0, stream>>>(src, dst, ety, histG,
                                                 bsum, ebuf, E, NB, chunk);
    k_localcsr<<<NB, 256, 0, stream>>>(ebuf, bsum, a_src, a_dst, a_ee, b2,
                                       rp, wexp, dsum, N, NB, E);
    k_out<<<(N + 3) / 4, 256, 0, stream>>>(rp, ebuf, wexp, dsum, keys, edge_emb, out, N);
}

// Round 19
// 82.582 us; speedup vs baseline: 1.3034x; 1.3034x over previous
//
#include <hip/hip_runtime.h>
#include <hip/hip_bf16.h>
#include <hip/hip_fp16.h>

// GAT layer, CSR-by-destination (R15/R17 structure), ~12.2 MB ws, zero global
// atomics, 5 launches:
//   keys = inputs @ W1 + b1            (stored bf16; alphas from f32 accumulator)
//   logit[e] = leaky(a_src[s] + a_dst[d] + a_ee[ty] + b2)
//   attn = exp/segsum ; out[d] = sum attn*(keys[s]+ee[ty])
// R18 lesson: 2-row GEMM blew VGPR 36->188 (occupancy 9%) -> 3x slower. Theory
// (LDS-issue-bound GEMM) stands; fix is register discipline:
// R19: 2-row GEMM + __launch_bounds__(256,4) cap + partial unroll + loop epilogue.

__device__ __forceinline__ unsigned short f2bf(float f) {
    unsigned u = __float_as_uint(f);
    u += 0x7FFFu + ((u >> 16) & 1u);          // round-nearest-even
    return (unsigned short)(u >> 16);
}
__device__ __forceinline__ float bf2f(unsigned short h) {
    return __uint_as_float(((unsigned)h) << 16);
}

#define NBLK_H 256        // edge chunks for histogram/scatter
#define CAPB   16384      // LDS edge-stage capacity per bucket (4x statistical max)

// GEMM (32 rows/block, 2 rows per 16-lane group) + alphas + fused histogram
__global__ __launch_bounds__(256, 4) void k_nodes(
    const float* __restrict__ inputs, const float* __restrict__ W1,
    const float* __restrict__ b1, const float* __restrict__ W2,
    const float* __restrict__ edge_emb, const int* __restrict__ dst,
    unsigned short* __restrict__ keys, float* __restrict__ alpha_src,
    float* __restrict__ alpha_dst, float* __restrict__ alpha_ee,
    int* __restrict__ histG, int N, int E, int NB, int chunk)
{
    __shared__ float W1s[64 * 64];
    __shared__ float W2s[128];
    __shared__ float xs[32 * 65];
    __shared__ int histL[256];

    const int t = threadIdx.x;
    const int row0 = blockIdx.x * 32;

    const float4* W1g = reinterpret_cast<const float4*>(W1);
    float4* W1sv = reinterpret_cast<float4*>(W1s);
#pragma unroll
    for (int i = 0; i < 4; i++) W1sv[t + 256 * i] = W1g[t + 256 * i];
    if (t < 128) W2s[t] = W2[t];

    for (int i = 0; i < 8; i++) {
        int idx = t + 256 * i;               // 0..2047
        int r = idx >> 6, c = idx & 63;
        if (row0 + r < N)
            xs[r * 65 + c] = inputs[(size_t)(row0 + r) * 64 + c];
    }
    __syncthreads();

    const int lane = t & 63;
    const int wave = t >> 6;
    const int gidx = wave * 4 + (lane >> 4);   // 16-lane group id 0..15
    const int j4   = lane & 15;                // float4 column group
    const int rA = 2 * gidx;

    const float4* W1v = reinterpret_cast<const float4*>(W1s);
    float4 acc[2];
    acc[0] = {0.f, 0.f, 0.f, 0.f};
    acc[1] = {0.f, 0.f, 0.f, 0.f};
#pragma unroll 4
    for (int k = 0; k < 64; k++) {
        float4 w = W1v[k * 16 + j4];           // one b128 read feeds 8 FMA
        float a0 = xs[rA * 65 + k];
        float a1 = xs[rA * 65 + 65 + k];
        acc[0].x += a0 * w.x; acc[0].y += a0 * w.y;
        acc[0].z += a0 * w.z; acc[0].w += a0 * w.w;
        acc[1].x += a1 * w.x; acc[1].y += a1 * w.y;
        acc[1].z += a1 * w.z; acc[1].w += a1 * w.w;
    }

    const float4 bv = reinterpret_cast<const float4*>(b1)[j4];
#pragma unroll
    for (int i = 0; i < 2; i++) {
        int row = row0 + rA + i;
        if (row < N) {
            float4 a = { acc[i].x + bv.x, acc[i].y + bv.y,
                         acc[i].z + bv.z, acc[i].w + bv.w };
            ushort4 kv;
            kv.x = f2bf(a.x); kv.y = f2bf(a.y); kv.z = f2bf(a.z); kv.w = f2bf(a.w);
            reinterpret_cast<ushort4*>(keys)[(size_t)row * 16 + j4] = kv;
            float p1 = a.x * W2s[4 * j4]     + a.y * W2s[4 * j4 + 1]
                     + a.z * W2s[4 * j4 + 2] + a.w * W2s[4 * j4 + 3];
            float p2 = a.x * W2s[64 + 4 * j4]     + a.y * W2s[64 + 4 * j4 + 1]
                     + a.z * W2s[64 + 4 * j4 + 2] + a.w * W2s[64 + 4 * j4 + 3];
#pragma unroll
            for (int m = 8; m >= 1; m >>= 1) {
                p1 += __shfl_xor(p1, m);
                p2 += __shfl_xor(p2, m);
            }
            if (j4 == 0) { alpha_src[row] = p1; alpha_dst[row] = p2; }
        }
    }

    if (blockIdx.x == 0 && t < 6) {
        float s = 0.f;
        for (int c = 0; c < 64; c++) s += edge_emb[t * 64 + c] * W2s[c];
        alpha_ee[t] = s;
    }

    // fused histogram (bucket = dst>>8): blockIdx uniform -> barriers safe
    if (blockIdx.x < NBLK_H) {
        const int blk = blockIdx.x;
        for (int b = t; b < NB; b += 256) histL[b] = 0;
        __syncthreads();
        const int lim = min(E, (blk + 1) * chunk);
        for (int e = blk * chunk + t; e < lim; e += 256)
            atomicAdd(&histL[dst[e] >> 8], 1);
        __syncthreads();
        for (int b = t; b < NB; b += 256)
            histG[b * NBLK_H + blk] = histL[b];
    }
}

// per-bucket row scan: exclusive over the 256 chunk-counts, total -> bsum[b]
__global__ __launch_bounds__(256) void k_scanA(
    int* __restrict__ histG, int* __restrict__ bsum)
{
    __shared__ int sm[256];
    const int t = threadIdx.x;
    const int b = blockIdx.x;
    int v = histG[b * NBLK_H + t];
    sm[t] = v;
    __syncthreads();
    for (int off = 1; off < 256; off <<= 1) {
        int x = 0;
        if (t >= off) x = sm[t - off];
        __syncthreads();
        if (t >= off) sm[t] += x;
        __syncthreads();
    }
    histG[b * NBLK_H + t] = sm[t] - v;     // exclusive
    if (t == 255) bsum[b] = sm[255];
}

// scatter into bucket-sorted order; boff derived locally from bsum (LDS scan)
__global__ __launch_bounds__(256) void k_bucket_scatter(
    const int* __restrict__ src, const int* __restrict__ dst,
    const int* __restrict__ ety, const int* __restrict__ histG,
    const int* __restrict__ bsum, int* __restrict__ ebuf,
    int E, int NB, int chunk)
{
    __shared__ int sm[256];
    __shared__ int cur[256];
    const int t = threadIdx.x;
    const int blk = blockIdx.x;

    int bs = (t < NB) ? bsum[t] : 0;
    sm[t] = bs;
    __syncthreads();
    for (int off = 1; off < 256; off <<= 1) {
        int x = 0;
        if (t >= off) x = sm[t - off];
        __syncthreads();
        if (t >= off) sm[t] += x;
        __syncthreads();
    }
    if (t < NB) cur[t] = (sm[t] - bs) + histG[t * NBLK_H + blk];  // boff[t] + chunk offset
    __syncthreads();

    const int lim = min(E, (blk + 1) * chunk);
    for (int e = blk * chunk + t; e < lim; e += 256) {
        int d = dst[e];
        int pos = atomicAdd(&cur[d >> 8], 1);
        ebuf[pos] = src[e] | (ety[e] << 16) | ((d & 255) << 19);
    }
}

// one block per bucket: stage edges in LDS, 256-way sub-histogram + scan,
// write row_ptr, regroup in-place by dest, compute exp ONCE per edge ->
// wexp f16 (coalesced) + per-dest dsum via LDS float atomics.
__global__ __launch_bounds__(256) void k_localcsr(
    int* __restrict__ ebuf, const int* __restrict__ bsum,
    const float* __restrict__ a_src, const float* __restrict__ a_dst,
    const float* __restrict__ a_ee, const float* __restrict__ b2,
    int* __restrict__ rp, __half* __restrict__ wexp,
    float* __restrict__ dsum, int N, int NB, int E)
{
    __shared__ int   estage[CAPB];
    __shared__ int   h[256];
    __shared__ int   sm[256];
    __shared__ int   cur2[256];
    __shared__ float fsum[256];
    __shared__ float baseL[256];
    __shared__ float aeeL[8];

    const int t = threadIdx.x;
    const int b = blockIdx.x;
    const int idx = (b << 8) + t;

    int bs = (t < NB) ? bsum[t] : 0;
    sm[t] = bs;
    __syncthreads();
    for (int off = 1; off < 256; off <<= 1) {
        int x = 0;
        if (t >= off) x = sm[t - off];
        __syncthreads();
        if (t >= off) sm[t] += x;
        __syncthreads();
    }
    const int begB = (b == 0) ? 0 : sm[b - 1];
    const int endB = sm[b];
    const int cnt  = endB - begB;
    __syncthreads();

    h[t] = 0;
    fsum[t] = 0.f;
    baseL[t] = (idx < N) ? (a_dst[idx] + b2[0]) : 0.f;
    if (t < 6) aeeL[t] = a_ee[t];
    __syncthreads();

    for (int i = t; i < cnt; i += 256) {
        int r = ebuf[begB + i];
        if (i < CAPB) estage[i] = r;
        atomicAdd(&h[(r >> 19) & 255], 1);
    }
    __syncthreads();

    sm[t] = h[t];
    __syncthreads();
    for (int off = 1; off < 256; off <<= 1) {
        int x = 0;
        if (t >= off) x = sm[t - off];
        __syncthreads();
        if (t >= off) sm[t] += x;
        __syncthreads();
    }
    int lstart = (t == 0) ? 0 : sm[t - 1];

    if (idx < N) rp[idx] = begB + lstart;
    if (b == NB - 1 && t == 0) rp[N] = E;
    cur2[t] = begB + lstart;
    __syncthreads();

    for (int i = t; i < cnt; i += 256) {
        int r = (i < CAPB) ? estage[i] : ebuf[begB + i];
        int s  = r & 0xFFFF;
        int ty = (r >> 16) & 7;
        int dl = (r >> 19) & 255;
        float l = a_src[s] + aeeL[ty] + baseL[dl];
        l = fmaxf(0.2f * l, l);
        float w = expf(l);
        int pos = atomicAdd(&cur2[dl], 1);
        ebuf[pos] = r & 0x7FFFF;               // src | ty<<16
        wexp[pos] = __float2half_rn(w);
        atomicAdd(&fsum[dl], w);
    }
    __syncthreads();
    if (idx < N) dsum[idx] = fsum[t];
}

// one 64-lane wave per destination; exp-free single pass (x2 unroll).
__global__ __launch_bounds__(256) void k_out(
    const int* __restrict__ rp, const int* __restrict__ erec,
    const __half* __restrict__ wexp, const float* __restrict__ dsum,
    const unsigned short* __restrict__ keys, const float* __restrict__ edge_emb,
    float* __restrict__ out, int N)
{
    __shared__ float ee4[384];
    __shared__ int   srec[4][64];
    __shared__ float sw[4][64];

    const int t = threadIdx.x;
    for (int i = t; i < 384; i += 256) ee4[i] = edge_emb[i];
    __syncthreads();

    const int lane = t & 63;
    const int wid  = t >> 6;
    const int d = blockIdx.x * 4 + wid;
    if (d >= N) return;

    const int beg = rp[d], end = rp[d + 1];
    const float inv = (end > beg) ? 1.f / dsum[d] : 0.f;

    const int g  = lane >> 4;
    const int j4 = lane & 15;
    const float4* ee4v = reinterpret_cast<const float4*>(ee4);
    float4 acc0 = {0.f, 0.f, 0.f, 0.f};
    float4 acc1 = {0.f, 0.f, 0.f, 0.f};

    for (int cbase = beg; cbase < end; cbase += 64) {
        const int n = min(64, end - cbase);
        if (lane < n) {
            srec[wid][lane] = erec[cbase + lane];
            sw[wid][lane]   = __half2float(wexp[cbase + lane]);
        }
        __builtin_amdgcn_wave_barrier();
        int j = g;
        for (; j + 4 < n; j += 8) {
            int   r0 = srec[wid][j];
            int   r1 = srec[wid][j + 4];
            float w0 = sw[wid][j];
            float w1 = sw[wid][j + 4];
            int sA = r0 & 0xFFFF, tyA = r0 >> 16;
            int sB = r1 & 0xFFFF, tyB = r1 >> 16;
            ushort4 kv0 = reinterpret_cast<const ushort4*>(keys)[(size_t)sA * 16 + j4];
            ushort4 kv1 = reinterpret_cast<const ushort4*>(keys)[(size_t)sB * 16 + j4];
            float4  ev0 = ee4v[tyA * 16 + j4];
            float4  ev1 = ee4v[tyB * 16 + j4];
            acc0.x += (bf2f(kv0.x) + ev0.x) * w0;
            acc0.y += (bf2f(kv0.y) + ev0.y) * w0;
            acc0.z += (bf2f(kv0.z) + ev0.z) * w0;
            acc0.w += (bf2f(kv0.w) + ev0.w) * w0;
            acc1.x += (bf2f(kv1.x) + ev1.x) * w1;
            acc1.y += (bf2f(kv1.y) + ev1.y) * w1;
            acc1.z += (bf2f(kv1.z) + ev1.z) * w1;
            acc1.w += (bf2f(kv1.w) + ev1.w) * w1;
        }
        if (j < n) {
            int   r0 = srec[wid][j];
            float w0 = sw[wid][j];
            int sA = r0 & 0xFFFF, tyA = r0 >> 16;
            ushort4 kv0 = reinterpret_cast<const ushort4*>(keys)[(size_t)sA * 16 + j4];
            float4  ev0 = ee4v[tyA * 16 + j4];
            acc0.x += (bf2f(kv0.x) + ev0.x) * w0;
            acc0.y += (bf2f(kv0.y) + ev0.y) * w0;
            acc0.z += (bf2f(kv0.z) + ev0.z) * w0;
            acc0.w += (bf2f(kv0.w) + ev0.w) * w0;
        }
        __builtin_amdgcn_wave_barrier();
    }

    float4 acc = { acc0.x + acc1.x, acc0.y + acc1.y,
                   acc0.z + acc1.z, acc0.w + acc1.w };
#pragma unroll
    for (int m = 16; m <= 32; m <<= 1) {
        acc.x += __shfl_xor(acc.x, m);
        acc.y += __shfl_xor(acc.y, m);
        acc.z += __shfl_xor(acc.z, m);
        acc.w += __shfl_xor(acc.w, m);
    }
    if (g == 0) {
        acc.x *= inv; acc.y *= inv; acc.z *= inv; acc.w *= inv;
        reinterpret_cast<float4*>(out)[(size_t)d * 16 + j4] = acc;
    }
}

extern "C" void kernel_launch(void* const* d_in, const int* in_sizes, int n_in,
                              void* d_out, int out_size, void* d_ws, size_t ws_size,
                              hipStream_t stream) {
    const float* inputs   = (const float*)d_in[0];
    const int*   src      = (const int*)d_in[1];
    const int*   dst      = (const int*)d_in[2];
    const int*   ety      = (const int*)d_in[3];
    const float* W1       = (const float*)d_in[5];
    const float* b1       = (const float*)d_in[6];
    const float* W2       = (const float*)d_in[7];
    const float* b2       = (const float*)d_in[8];
    const float* edge_emb = (const float*)d_in[9];
    float* out = (float*)d_out;

    const int N  = in_sizes[0] / 64;
    const int E  = in_sizes[1];
    const int NB = (N + 255) >> 8;          // 196 buckets of 256 dests
    const int M  = NB * NBLK_H;             // histG length (bucket-major)
    const int chunk = (E + NBLK_H - 1) / NBLK_H;

    // workspace layout in 4-byte units; total ~12.2 MB
    float*          ws      = (float*)d_ws;
    unsigned short* keys    = (unsigned short*)ws;          // N*64 bf16 = N*32 ints
    float*          a_src   = ws + (size_t)N * 32;          // N
    float*          a_dst   = a_src + N;                    // N
    float*          a_ee    = a_dst + N;                    // 8
    int*            rp      = (int*)(a_ee + 8);             // N+2
    int*            histG   = rp + (N + 2);                 // M
    int*            bsum    = histG + M;                    // 256
    int*            ebuf    = bsum + 256;                   // E
    __half*         wexp    = (__half*)(ebuf + E);          // E halves
    float*          dsum    = (float*)(wexp + ((E + 1) & ~1)); // N

    int nblk = (N + 31) / 32;               // 1563 blocks (>=256 for hist)
    k_nodes<<<nblk, 256, 0, stream>>>(inputs, W1, b1, W2, edge_emb, dst,
                                      keys, a_src, a_dst, a_ee, histG, N, E, NB, chunk);
    k_scanA<<<NB, 256, 0, stream>>>(histG, bsum);
    k_bucket_scatter<<<NBLK_H, 256, 0, stream>>>(src, dst, ety, histG,
                                                 bsum, ebuf, E, NB, chunk);
    k_localcsr<<<NB, 256, 0, stream>>>(ebuf, bsum, a_src, a_dst, a_ee, b2,
                                       rp, wexp, dsum, N, NB, E);
    k_out<<<(N + 3) / 4, 256, 0, stream>>>(rp, ebuf, wexp, dsum, keys, edge_emb, out, N);
}